// Round 2
// baseline (417.345 us; speedup 1.0000x reference)
//
#include <hip/hip_runtime.h>

// SSM4D: causal depthwise conv1d, B=16, C=1024, T=3000, K=24, fp32.
// y[b,c,t] = sum_{d=0..23} w[c][d] * x[b,c,t-d],  w[c][d] = kern[c][K-1-d]
// kern[c][k] = beta[c] * exp(log(max(alpha[c],1e-6))*k) * cos4(theta[c]*k)
//
// R4: single fused kernel. R3's A/B (OPT=8 bad-stride vs OPT=4 coalesced)
// was neutral -> conv is not load-pattern bound; remaining suspects are the
// costs R2/R3 shared: separate weights pre-kernel (launch + serialization),
// per-block global weight fetches (49k blocks x 96B), block granularity.
// Now: one block per row (16384 blocks), weights computed once per block
// into LDS (24 transcendentals, broadcast reads = conflict-free), 3 output
// tiles per block. No workspace, no pre-kernel.
// Roofline: 197MB read + 197MB write -> ~62us @ 6.3 TB/s for the conv.

#define KSZ   24
#define T_LEN 3000
#define C_CH  1024
#define B_N   16
#define OPT   4            // outputs per thread per tile (one float4)
#define TPB   256
#define TILE  (TPB * OPT)  // 1024
#define NTILE ((T_LEN + TILE - 1) / TILE)  // 3

__device__ __forceinline__ float cos_approx(float v) {
    float v2 = v * v;
    return 1.0f - 0.5f * v2 + (v2 * v2) * (1.0f / 24.0f);
}

__global__ __launch_bounds__(TPB) void ssm4d_fused(
        const float* __restrict__ x,
        const float* __restrict__ alpha,
        const float* __restrict__ beta,
        const float* __restrict__ theta,
        float* __restrict__ y) {
    const int row   = blockIdx.x;            // b*C + c
    const int c     = row & (C_CH - 1);
    const long base = (long)row * T_LEN;

    // weights once per block: same formula as the old pre-kernel (bit-identical)
    __shared__ float ws[KSZ];
    if (threadIdx.x < KSZ) {
        const int k = (KSZ - 1) - threadIdx.x;            // flip for causal FIR
        const float a   = fmaxf(alpha[c], 1e-6f);
        const float dec = expf(logf(a) * (float)k);
        ws[threadIdx.x] = beta[c] * dec * cos_approx(theta[c] * (float)k);
    }
    __syncthreads();

    float wr[KSZ];
#pragma unroll
    for (int d = 0; d < KSZ; ++d) wr[d] = ws[d];          // uniform-addr broadcast

    for (int tile = 0; tile < NTILE; ++tile) {
        const int t = tile * TILE + threadIdx.x * OPT;    // first output of this chunk
        if (t >= T_LEN) break;                            // t monotone in tile
        // window win[p] = x[t - 24 + p], p = 0..27 (win[0] unused)
        float win[KSZ + OPT];
        if (t >= KSZ) {
            const float4* xp = (const float4*)(x + base + t - KSZ);  // 16B aligned
#pragma unroll
            for (int q = 0; q < (KSZ + OPT) / 4; ++q) {
                float4 v = xp[q];
                win[4 * q + 0] = v.x; win[4 * q + 1] = v.y;
                win[4 * q + 2] = v.z; win[4 * q + 3] = v.w;
            }
        } else {
            // only threads 0..5 of tile 0: causal zero-pad
#pragma unroll
            for (int p = 0; p < KSZ + OPT; ++p) {
                const int idx = t - KSZ + p;
                win[p] = (idx >= 0) ? x[base + idx] : 0.0f;
            }
        }

        float acc[OPT];
#pragma unroll
        for (int m = 0; m < OPT; ++m) acc[m] = 0.0f;
#pragma unroll
        for (int d = 0; d < KSZ; ++d) {
#pragma unroll
            for (int m = 0; m < OPT; ++m)
                acc[m] = fmaf(wr[d], win[KSZ + m - d], acc[m]);  // y[t+m] += w[d]*x[t+m-d]
        }

        *(float4*)(y + base + t) = make_float4(acc[0], acc[1], acc[2], acc[3]);
    }
}

extern "C" void kernel_launch(void* const* d_in, const int* in_sizes, int n_in,
                              void* d_out, int out_size, void* d_ws, size_t ws_size,
                              hipStream_t stream) {
    const float* x     = (const float*)d_in[0];
    const float* alpha = (const float*)d_in[1];
    const float* beta  = (const float*)d_in[2];
    const float* theta = (const float*)d_in[3];
    float* y = (float*)d_out;

    ssm4d_fused<<<B_N * C_CH, TPB, 0, stream>>>(x, alpha, beta, theta, y);
}

// Round 4
// 341.137 us; speedup vs baseline: 1.2234x; 1.2234x over previous
//
#include <hip/hip_runtime.h>

// SSM4D: causal depthwise conv1d, B=16, C=1024, T=3000, K=24, fp32.
// y[b,c,t] = sum_{d=0..23} w[c][d] * x[b,c,t-d],  w[c][d] = kern[c][K-1-d]
// kern[c][k] = beta[c] * exp(log(max(alpha[c],1e-6))*k) * cos4(theta[c]*k)
//
// R6 = R5 with the compile fix: __builtin_nontemporal_store needs a native
// clang vector type, not HIP_vector_type<float,4>. Use ext_vector_type(4).
// Structure: R3's flat grid (one tile per thread, 49152 blocks — max MLP;
// R4's 3-tile serial loop was latency-bound at 1.57 TB/s, VALUBusy 17%) +
// in-block weight computation via LDS (kills the pre-kernel dispatch) +
// nontemporal y stores (y is write-once; keep L2/L3 for x -> lower FETCH).
// Early-exit AFTER __syncthreads (partial-wave exit before barrier = hazard).
// Roofline: ~197MB read + ~193MB write -> ~62us @ 6.3 TB/s.

#define KSZ   24
#define T_LEN 3000
#define C_CH  1024
#define B_N   16
#define OPT   4            // outputs per thread (one float4)
#define TPB   256
#define TILE  (TPB * OPT)  // 1024

typedef float f32x4 __attribute__((ext_vector_type(4)));

__device__ __forceinline__ float cos_approx(float v) {
    float v2 = v * v;
    return 1.0f - 0.5f * v2 + (v2 * v2) * (1.0f / 24.0f);
}

__global__ __launch_bounds__(TPB) void ssm4d_conv(
        const float* __restrict__ x,
        const float* __restrict__ alpha,
        const float* __restrict__ beta,
        const float* __restrict__ theta,
        float* __restrict__ y) {
    const int row   = blockIdx.y;            // b*C + c
    const int c     = row & (C_CH - 1);
    const long base = (long)row * T_LEN;

    // weights once per block (same formula as the old pre-kernel, bit-identical)
    __shared__ float ws[KSZ];
    if (threadIdx.x < KSZ) {
        const int k = (KSZ - 1) - threadIdx.x;            // flip for causal FIR
        const float a   = fmaxf(alpha[c], 1e-6f);
        const float dec = expf(logf(a) * (float)k);
        ws[threadIdx.x] = beta[c] * dec * cos_approx(theta[c] * (float)k);
    }
    __syncthreads();

    const int t = blockIdx.x * TILE + threadIdx.x * OPT;  // first output
    if (t < T_LEN) {                                      // tail: t>=3000 idle
        float wr[KSZ];
#pragma unroll
        for (int d = 0; d < KSZ; ++d) wr[d] = ws[d];      // uniform-addr broadcast

        // window win[p] = x[t - 24 + p], p = 0..27 (win[0] unused)
        // 7 float4 loads, lane stride 16B: contiguous 1KB wave xacts, L1
        // absorbs the 7x overlap.
        float win[KSZ + OPT];
        if (t >= KSZ) {
            const float4* xp = (const float4*)(x + base + t - KSZ);  // 16B aligned
#pragma unroll
            for (int q = 0; q < (KSZ + OPT) / 4; ++q) {
                float4 v = xp[q];
                win[4 * q + 0] = v.x; win[4 * q + 1] = v.y;
                win[4 * q + 2] = v.z; win[4 * q + 3] = v.w;
            }
        } else {
            // only threads 0..5 of blockIdx.x==0: causal zero-pad
#pragma unroll
            for (int p = 0; p < KSZ + OPT; ++p) {
                const int idx = t - KSZ + p;
                win[p] = (idx >= 0) ? x[base + idx] : 0.0f;
            }
        }

        float acc[OPT];
#pragma unroll
        for (int m = 0; m < OPT; ++m) acc[m] = 0.0f;
#pragma unroll
        for (int d = 0; d < KSZ; ++d) {
#pragma unroll
            for (int m = 0; m < OPT; ++m)
                acc[m] = fmaf(wr[d], win[KSZ + m - d], acc[m]);  // y[t+m] += w[d]*x[t+m-d]
        }

        // y is write-once, never re-read: nontemporal keeps L2/L3 for x
        f32x4 out = { acc[0], acc[1], acc[2], acc[3] };
        __builtin_nontemporal_store(out, (f32x4*)(y + base + t));
    }
}

extern "C" void kernel_launch(void* const* d_in, const int* in_sizes, int n_in,
                              void* d_out, int out_size, void* d_ws, size_t ws_size,
                              hipStream_t stream) {
    const float* x     = (const float*)d_in[0];
    const float* alpha = (const float*)d_in[1];
    const float* beta  = (const float*)d_in[2];
    const float* theta = (const float*)d_in[3];
    float* y = (float*)d_out;

    dim3 grid((T_LEN + TILE - 1) / TILE, B_N * C_CH);   // (3, 16384)
    ssm4d_conv<<<grid, TPB, 0, stream>>>(x, alpha, beta, theta, y);
}